// Round 2
// baseline (3291.733 us; speedup 1.0000x reference)
//
#include <hip/hip_runtime.h>
#include <math.h>

#define BB 4
#define SS 1024
#define HIDD 1024
#define NH 32
#define HD 32
#define RS 0.17677669529663687f   // 1/sqrt(32)

// ---------------------------------------------------------------------------
// GEMM: Y = X @ W^T + b   (X: M x 1024 row-major, W: N x 1024 row-major)
// 128x128 tile, BK=16, 256 threads, 8x8 per-thread microtile in two 4-wide
// groups (rows {4tx, 64+4tx}, cols {4ty, 64+4ty}) -> 2-way LDS aliasing only.
// ---------------------------------------------------------------------------
#define BM 128
#define BN 128
#define BK 16

__global__ __launch_bounds__(256) void gemm_qkv(
    const float* __restrict__ X,
    const float* __restrict__ W0, const float* __restrict__ W1, const float* __restrict__ W2,
    const float* __restrict__ c0, const float* __restrict__ c1, const float* __restrict__ c2,
    float* __restrict__ O0, float* __restrict__ O1, float* __restrict__ O2)
{
    const int zi = blockIdx.z;
    const float* Wm = (zi == 0) ? W0 : (zi == 1 ? W1 : W2);
    const float* bm = (zi == 0) ? c0 : (zi == 1 ? c1 : c2);
    float* Om       = (zi == 0) ? O0 : (zi == 1 ? O1 : O2);

    const int i0 = blockIdx.x * BM;
    const int j0 = blockIdx.y * BN;
    const int tid = threadIdx.x;
    const int tx = tid & 15, ty = tid >> 4;
    const int ra = tx * 4, rb = 64 + tx * 4;
    const int ca = ty * 4, cb = 64 + ty * 4;

    __shared__ float As[BK][BM + 4];
    __shared__ float Bs[BK][BN + 4];

    float acc[8][8] = {};

    for (int k0 = 0; k0 < 1024; k0 += BK) {
        #pragma unroll
        for (int f0 = 0; f0 < 2; ++f0) {
            int f = tid + f0 * 256;          // 0..511
            int r = f >> 2;                  // 0..127
            int c4 = (f & 3) * 4;            // 0,4,8,12
            float4 a = *(const float4*)&X[(size_t)(i0 + r) * 1024 + k0 + c4];
            As[c4 + 0][r] = a.x; As[c4 + 1][r] = a.y;
            As[c4 + 2][r] = a.z; As[c4 + 3][r] = a.w;
            float4 w = *(const float4*)&Wm[(size_t)(j0 + r) * 1024 + k0 + c4];
            Bs[c4 + 0][r] = w.x; Bs[c4 + 1][r] = w.y;
            Bs[c4 + 2][r] = w.z; Bs[c4 + 3][r] = w.w;
        }
        __syncthreads();
        #pragma unroll
        for (int k = 0; k < BK; ++k) {
            float ar[8], br[8];
            *(float4*)&ar[0] = *(const float4*)&As[k][ra];
            *(float4*)&ar[4] = *(const float4*)&As[k][rb];
            *(float4*)&br[0] = *(const float4*)&Bs[k][ca];
            *(float4*)&br[4] = *(const float4*)&Bs[k][cb];
            #pragma unroll
            for (int mm = 0; mm < 8; ++mm)
                #pragma unroll
                for (int nn = 0; nn < 8; ++nn)
                    acc[mm][nn] += ar[mm] * br[nn];
        }
        __syncthreads();
    }

    // epilogue: write into (B, NH, S, HD) layout
    #pragma unroll
    for (int mm = 0; mm < 8; ++mm) {
        int i = i0 + ((mm < 4) ? (ra + mm) : (rb + mm - 4));
        int bi = i >> 10, si = i & 1023;
        #pragma unroll
        for (int g = 0; g < 2; ++g) {
            int j = j0 + (g == 0 ? ca : cb);
            int h = j >> 5, d = j & 31;
            float4 o;
            o.x = acc[mm][g*4 + 0] + bm[j + 0];
            o.y = acc[mm][g*4 + 1] + bm[j + 1];
            o.z = acc[mm][g*4 + 2] + bm[j + 2];
            o.w = acc[mm][g*4 + 3] + bm[j + 3];
            *(float4*)&Om[(((size_t)bi * NH + h) * SS + si) * HD + d] = o;
        }
    }
}

__global__ __launch_bounds__(256) void gemm_out(
    const float* __restrict__ X, const float* __restrict__ Wm,
    const float* __restrict__ bm, const float* __restrict__ res,
    float* __restrict__ Om)
{
    const int i0 = blockIdx.x * BM;
    const int j0 = blockIdx.y * BN;
    const int tid = threadIdx.x;
    const int tx = tid & 15, ty = tid >> 4;
    const int ra = tx * 4, rb = 64 + tx * 4;
    const int ca = ty * 4, cb = 64 + ty * 4;

    __shared__ float As[BK][BM + 4];
    __shared__ float Bs[BK][BN + 4];

    float acc[8][8] = {};

    for (int k0 = 0; k0 < 1024; k0 += BK) {
        #pragma unroll
        for (int f0 = 0; f0 < 2; ++f0) {
            int f = tid + f0 * 256;
            int r = f >> 2;
            int c4 = (f & 3) * 4;
            float4 a = *(const float4*)&X[(size_t)(i0 + r) * 1024 + k0 + c4];
            As[c4 + 0][r] = a.x; As[c4 + 1][r] = a.y;
            As[c4 + 2][r] = a.z; As[c4 + 3][r] = a.w;
            float4 w = *(const float4*)&Wm[(size_t)(j0 + r) * 1024 + k0 + c4];
            Bs[c4 + 0][r] = w.x; Bs[c4 + 1][r] = w.y;
            Bs[c4 + 2][r] = w.z; Bs[c4 + 3][r] = w.w;
        }
        __syncthreads();
        #pragma unroll
        for (int k = 0; k < BK; ++k) {
            float ar[8], br[8];
            *(float4*)&ar[0] = *(const float4*)&As[k][ra];
            *(float4*)&ar[4] = *(const float4*)&As[k][rb];
            *(float4*)&br[0] = *(const float4*)&Bs[k][ca];
            *(float4*)&br[4] = *(const float4*)&Bs[k][cb];
            #pragma unroll
            for (int mm = 0; mm < 8; ++mm)
                #pragma unroll
                for (int nn = 0; nn < 8; ++nn)
                    acc[mm][nn] += ar[mm] * br[nn];
        }
        __syncthreads();
    }

    #pragma unroll
    for (int mm = 0; mm < 8; ++mm) {
        int i = i0 + ((mm < 4) ? (ra + mm) : (rb + mm - 4));
        #pragma unroll
        for (int g = 0; g < 2; ++g) {
            int j = j0 + (g == 0 ? ca : cb);
            float4 r4 = *(const float4*)&res[(size_t)i * 1024 + j];
            float4 o;
            o.x = acc[mm][g*4 + 0] + bm[j + 0] + r4.x;
            o.y = acc[mm][g*4 + 1] + bm[j + 1] + r4.y;
            o.z = acc[mm][g*4 + 2] + bm[j + 2] + r4.z;
            o.w = acc[mm][g*4 + 3] + bm[j + 3] + r4.w;
            *(float4*)&Om[(size_t)i * 1024 + j] = o;
        }
    }
}

// ---------------------------------------------------------------------------
// Attention v2. Block = 32 q-rows of one (b,h). 256 threads.
// Thread (rg = tid>>4, cg = tid&15) owns rows {2rg, 2rg+1} and, per 128-col
// K tile, cols {64*u4 + 4*cg + uu} -> coalesced float4 probs stores.
// K/V tiles 128x32 in LDS with XOR swizzle (d4 ^= (c>>3)&7): conflict-free.
// Pass 1: online (m,l). Pass 2: recompute scores, write probs, accumulate PV.
// ---------------------------------------------------------------------------
__global__ __launch_bounds__(256, 3) void attn_kernel(
    const float* __restrict__ Q, const float* __restrict__ K,
    const float* __restrict__ V, const float* __restrict__ dist,
    float* __restrict__ probs, float* __restrict__ ctx)
{
    const int q0 = blockIdx.x * 32;
    const int h  = blockIdx.y;
    const int b  = blockIdx.z;
    const int tid = threadIdx.x;
    const int rg = tid >> 4;          // 0..15
    const int cg = tid & 15;          // 0..15
    const size_t bh = (size_t)(b * NH + h);
    const float* Qh = Q + bh * SS * HD;
    const float* Kh = K + bh * SS * HD;
    const float* Vh = V + bh * SS * HD;
    float* Ph = probs + bh * SS * SS;

    __shared__ float Qs[32 * 32];     // swizzled
    __shared__ float Kt[128 * 32];    // swizzled
    __shared__ float Vt[128 * 32];    // swizzled
    __shared__ float dl[1055];        // dist window, column h

    // stage Q (swizzled) and dist window
    {
        int r = tid >> 3, d4 = tid & 7;
        float4 qv = *(const float4*)&Qh[(size_t)(q0 + r) * HD + d4 * 4];
        *(float4*)&Qs[r * 32 + ((d4 ^ (r & 7)) << 2)] = qv;
        for (int t = tid; t < 1055; t += 256)
            dl[t] = dist[(size_t)(q0 + t) * HD + h];
    }

    // stage a 128x32 K/V tile into LDS with XOR swizzle
    auto stage = [&](float* lds, const float* src, int c0) {
        #pragma unroll
        for (int it = 0; it < 4; ++it) {
            int f4 = tid + it * 256;        // float4 index 0..1023
            int c = f4 >> 3;                // key row 0..127
            int d4 = f4 & 7;
            float4 v = *(const float4*)&src[(size_t)(c0 + c) * HD + d4 * 4];
            *(float4*)&lds[c * 32 + ((d4 ^ ((c >> 3) & 7)) << 2)] = v;
        }
    };

    const int r0l = rg * 2, r1l = rg * 2 + 1;

    // QK^T for one staged tile -> 2x8 scaled+biased scores
    auto qk_tile = [&](const float* Kb, int c0, float sv[2][8]) {
        #pragma unroll
        for (int i = 0; i < 2; ++i)
            #pragma unroll
            for (int u = 0; u < 8; ++u) sv[i][u] = 0.f;
        #pragma unroll
        for (int d4 = 0; d4 < 8; ++d4) {
            float4 qa = *(const float4*)&Qs[r0l * 32 + ((d4 ^ (r0l & 7)) << 2)];
            float4 qb = *(const float4*)&Qs[r1l * 32 + ((d4 ^ (r1l & 7)) << 2)];
            #pragma unroll
            for (int u = 0; u < 8; ++u) {
                const int cl = ((u >> 2) << 6) + (cg << 2) + (u & 3);
                float4 kv = *(const float4*)&Kb[cl * 32 + ((d4 ^ ((cl >> 3) & 7)) << 2)];
                sv[0][u] += qa.x*kv.x + qa.y*kv.y + qa.z*kv.z + qa.w*kv.w;
                sv[1][u] += qb.x*kv.x + qb.y*kv.y + qb.z*kv.z + qb.w*kv.w;
            }
        }
        #pragma unroll
        for (int i = 0; i < 2; ++i)
            #pragma unroll
            for (int u = 0; u < 8; ++u) {
                const int cl = ((u >> 2) << 6) + (cg << 2) + (u & 3);
                sv[i][u] = (sv[i][u] + dl[r0l + i + 1023 - c0 - cl]) * RS;
            }
    };

    float mr[2] = {-1e30f, -1e30f}, lr[2] = {0.f, 0.f};

    auto ml_update = [&](float sv[2][8]) {
        #pragma unroll
        for (int i = 0; i < 2; ++i) {
            float tm = sv[i][0];
            #pragma unroll
            for (int u = 1; u < 8; ++u) tm = fmaxf(tm, sv[i][u]);
            float M = fmaxf(mr[i], tm);
            lr[i] *= __expf(mr[i] - M);
            mr[i] = M;
            #pragma unroll
            for (int u = 0; u < 8; ++u) lr[i] += __expf(sv[i][u] - M);
        }
    };

    // ---- pass 1: (m, l) over all keys; double tile per barrier pair ----
    for (int t = 0; t < 8; t += 2) {
        __syncthreads();
        stage(Kt, Kh, t * 128);
        stage(Vt, Kh, (t + 1) * 128);
        __syncthreads();
        float sv[2][8];
        qk_tile(Kt, t * 128, sv);       ml_update(sv);
        qk_tile(Vt, (t + 1) * 128, sv); ml_update(sv);
    }

    // merge (m,l) across the 16 cg lanes (butterfly)
    #pragma unroll
    for (int off = 1; off < 16; off <<= 1) {
        #pragma unroll
        for (int i = 0; i < 2; ++i) {
            float mo = __shfl_xor(mr[i], off);
            float lo = __shfl_xor(lr[i], off);
            float M = fmaxf(mr[i], mo);
            lr[i] = lr[i] * __expf(mr[i] - M) + lo * __expf(mo - M);
            mr[i] = M;
        }
    }
    const float rl0 = 1.f / lr[0], rl1 = 1.f / lr[1];

    // ---- pass 2: probs + PV ----
    float ca0[32] = {}, ca1[32] = {};
    for (int t = 0; t < 8; ++t) {
        const int c0 = t * 128;
        __syncthreads();
        stage(Kt, Kh, c0);
        stage(Vt, Vh, c0);
        __syncthreads();
        float sv[2][8];
        qk_tile(Kt, c0, sv);
        float p0[8], p1[8];
        #pragma unroll
        for (int u = 0; u < 8; ++u) {
            p0[u] = __expf(sv[0][u] - mr[0]) * rl0;
            p1[u] = __expf(sv[1][u] - mr[1]) * rl1;
        }
        // coalesced probs stores: 16 cg lanes cover 64 consecutive floats
        #pragma unroll
        for (int u4 = 0; u4 < 2; ++u4) {
            int cbase = c0 + u4 * 64 + (cg << 2);
            *(float4*)&Ph[(size_t)(q0 + r0l) * SS + cbase] =
                make_float4(p0[u4*4+0], p0[u4*4+1], p0[u4*4+2], p0[u4*4+3]);
            *(float4*)&Ph[(size_t)(q0 + r1l) * SS + cbase] =
                make_float4(p1[u4*4+0], p1[u4*4+1], p1[u4*4+2], p1[u4*4+3]);
        }
        // PV accumulate
        #pragma unroll
        for (int u = 0; u < 8; ++u) {
            const int cl = ((u >> 2) << 6) + (cg << 2) + (u & 3);
            const float pa = p0[u], pb = p1[u];
            #pragma unroll
            for (int d4 = 0; d4 < 8; ++d4) {
                float4 vv = *(const float4*)&Vt[cl * 32 + ((d4 ^ ((cl >> 3) & 7)) << 2)];
                ca0[d4*4+0] += pa*vv.x; ca0[d4*4+1] += pa*vv.y;
                ca0[d4*4+2] += pa*vv.z; ca0[d4*4+3] += pa*vv.w;
                ca1[d4*4+0] += pb*vv.x; ca1[d4*4+1] += pb*vv.y;
                ca1[d4*4+2] += pb*vv.z; ca1[d4*4+3] += pb*vv.w;
            }
        }
    }

    // reduce ctx partials across the 16 cg lanes (butterfly, all lanes end full)
    #pragma unroll
    for (int off = 1; off < 16; off <<= 1) {
        #pragma unroll
        for (int d = 0; d < 32; ++d) {
            ca0[d] += __shfl_xor(ca0[d], off);
            ca1[d] += __shfl_xor(ca1[d], off);
        }
    }
    // lane cg writes d = {2cg, 2cg+1}; 16 lanes cover the 32-float head slice
    {
        float* cp0 = ctx + ((size_t)(b * SS + q0 + r0l)) * HIDD + h * HD;
        float* cp1 = ctx + ((size_t)(b * SS + q0 + r1l)) * HIDD + h * HD;
        *(float2*)&cp0[cg * 2] = make_float2(ca0[cg*2], ca0[cg*2+1]);
        *(float2*)&cp1[cg * 2] = make_float2(ca1[cg*2], ca1[cg*2+1]);
    }
}

// ---------------------------------------------------------------------------
// Row LayerNorm: one block (256 threads) per row of 1024.
// ---------------------------------------------------------------------------
__global__ __launch_bounds__(256) void ln_kernel(
    const float* __restrict__ X, const float* __restrict__ gamma,
    const float* __restrict__ beta, float* __restrict__ out)
{
    const int row = blockIdx.x;
    const int tid = threadIdx.x;
    const float* xr = X + (size_t)row * 1024;
    float4 x = *(const float4*)&xr[tid * 4];
    float s = x.x + x.y + x.z + x.w;
    float q = x.x*x.x + x.y*x.y + x.z*x.z + x.w*x.w;
    #pragma unroll
    for (int off = 32; off; off >>= 1) {
        s += __shfl_xor(s, off);
        q += __shfl_xor(q, off);
    }
    __shared__ float ps[4], pq[4];
    int wid = tid >> 6, lane = tid & 63;
    if (lane == 0) { ps[wid] = s; pq[wid] = q; }
    __syncthreads();
    s = ps[0] + ps[1] + ps[2] + ps[3];
    q = pq[0] + pq[1] + pq[2] + pq[3];
    float mu = s * (1.0f / 1024.0f);
    float var = q * (1.0f / 1024.0f) - mu * mu;
    float rstd = 1.0f / sqrtf(var + 1e-12f);
    float4 g = *(const float4*)&gamma[tid * 4];
    float4 bt = *(const float4*)&beta[tid * 4];
    float4 o;
    o.x = (x.x - mu) * rstd * g.x + bt.x;
    o.y = (x.y - mu) * rstd * g.y + bt.y;
    o.z = (x.z - mu) * rstd * g.z + bt.z;
    o.w = (x.w - mu) * rstd * g.w + bt.w;
    *(float4*)&out[(size_t)row * 1024 + tid * 4] = o;
}

// ---------------------------------------------------------------------------
extern "C" void kernel_launch(void* const* d_in, const int* in_sizes, int n_in,
                              void* d_out, int out_size, void* d_ws, size_t ws_size,
                              hipStream_t stream)
{
    const float* hid  = (const float*)d_in[0];
    const float* Wq   = (const float*)d_in[1];
    const float* bq   = (const float*)d_in[2];
    const float* Wk   = (const float*)d_in[3];
    const float* bk   = (const float*)d_in[4];
    const float* Wv   = (const float*)d_in[5];
    const float* bvv  = (const float*)d_in[6];
    const float* Wo   = (const float*)d_in[7];
    const float* bo   = (const float*)d_in[8];
    const float* lng  = (const float*)d_in[9];
    const float* lnb  = (const float*)d_in[10];
    const float* dist = (const float*)d_in[11];

    float* out   = (float*)d_out;
    float* probs = out + (size_t)BB * SS * HIDD;   // probs follow out

    const size_t QN = (size_t)BB * NH * SS * HD;   // 4M floats
    float* ws   = (float*)d_ws;
    float* Qb   = ws;
    float* Kb   = ws + QN;
    float* Vb   = ws + 2 * QN;
    float* ctxb = ws + 3 * QN;
    float* xres = ws;                              // reuse Qb after attention

    gemm_qkv<<<dim3(32, 8, 3), 256, 0, stream>>>(hid, Wq, Wk, Wv, bq, bk, bvv, Qb, Kb, Vb);
    attn_kernel<<<dim3(32, NH, BB), 256, 0, stream>>>(Qb, Kb, Vb, dist, probs, ctxb);
    gemm_out<<<dim3(32, 8), 256, 0, stream>>>(ctxb, Wo, bo, hid, xres);
    ln_kernel<<<4096, 256, 0, stream>>>(xres, lng, lnb, out);
}